// Round 6
// baseline (42923.273 us; speedup 1.0000x reference)
//
#include <hip/hip_runtime.h>
#include <hip/hip_fp16.h>

// ============================================================================
// 2-layer LSTM with projection (proj_size=128, H=1024, B=64, T=2048)
//
// Round 6: ONE cross-WG hop per step (round 5 = 2 hops, 11.2 us/step).
//  - 8 WGs/layer x 512 threads (8 waves). Each WG owns H-slice of 128
//    (512 gate rows), gate weights register-resident (128 VGPR/lane).
//  - Per step: [poll 16 flags] -> each WG loads ALL 8 partial slabs of its
//    layer (256 KB sc1, coalesced) -> in-register sum -> h in LDS -> gate
//    MFMA [64,256]x[256,512] -> elementwise -> proj [64,128]x[128,128] ->
//    partial slab store (sc1) -> drain -> flag. No separate reduce phase.
//  - Layer coupling: l0 posts a tiny f16 h1 copy (A-frag layout, 2KB/WG)
//    to a 4-deep ring + f2 flag during its NEXT step's sum phase; l1 reads
//    it directly as gate A-fragments. l0 throttled by l1 flags >= t-4.
//  - All cross-WG data via round-5-proven relaxed AGENT-scope atomics
//    (__hip_atomic_*, lowers to global_* sc1, no cache maintenance).
//    Zero multi-output inline asm (rounds 3/4 lesson). fp32 slabs/c-state,
//    f16 weights/h (proven absmax 1.2e-4).
//  - Tails: t=TSTEPS extra iteration: l0 sums slabs(2047)->posts h1_2047;
//    l1 sums its slabs(2047)->writes last out rows. Timeout+canary kept.
// ============================================================================

typedef _Float16 f16;
typedef _Float16 f16x4 __attribute__((ext_vector_type(4)));
typedef _Float16 f16x8 __attribute__((ext_vector_type(8)));
typedef float f32x4 __attribute__((ext_vector_type(4)));
typedef unsigned long long u64;
struct U128 { u64 lo, hi; };

#define TSTEPS 2048
#define NWG 8
#define TIMEOUT_TICKS 200000000ull   // ~2 s at 100 MHz s_memrealtime

// ---- workspace layout (bytes) ----
#define BSW_OFF  0ull
#define BSW_SZ   (16ull*131072ull*2ull)        // gate weights, 4 MiB
#define WHR_OFF  (BSW_OFF + BSW_SZ)
#define WHR_SZ   (16ull*16384ull*2ull)         // proj weights, 512 KiB
#define BIAS_OFF (WHR_OFF + WHR_SZ)
#define BIAS_SZ  (8192ull*4ull)                // [lyr][w][512]
#define SLAB_OFF (BIAS_OFF + BIAS_SZ)
#define SLAB_SZ  (2ull*4ull*8ull*8192ull*4ull) // [lyr][slot4][wg8][8192 f32], 2 MiB
#define RING_OFF (SLAB_OFF + SLAB_SZ)
#define RING_SZ  (4ull*8192ull*2ull)           // h1 ring [slot4][8192 f16]
#define FLAG_OFF (RING_OFF + RING_SZ)
#define FLAG_SZ  (256ull)                      // int flags[0..7]=l0,[8..15]=l1,[16..23]=f2
#define WS_NEED  (FLAG_OFF + FLAG_SZ)

__device__ __forceinline__ float sigm(float v) {
  float e = __builtin_amdgcn_exp2f(-1.4426950408889634f * v);
  return __builtin_amdgcn_rcpf(1.0f + e);
}
__device__ __forceinline__ float tanh_(float v) {
  float a = fabsf(v);
  float e = __builtin_amdgcn_exp2f(-2.8853900817779268f * a);
  float r = (1.0f - e) * __builtin_amdgcn_rcpf(1.0f + e);
  return copysignf(r, v);
}

// ---- relaxed agent-scope atomic helpers (compile to global_* sc1) --------
__device__ __forceinline__ u64 ald64(const void* p) {
  return __hip_atomic_load((const u64*)p, __ATOMIC_RELAXED, __HIP_MEMORY_SCOPE_AGENT);
}
__device__ __forceinline__ void ast64(void* p, u64 v) {
  __hip_atomic_store((u64*)p, v, __ATOMIC_RELAXED, __HIP_MEMORY_SCOPE_AGENT);
}
__device__ __forceinline__ int ald32i(const int* p) {
  return __hip_atomic_load(p, __ATOMIC_RELAXED, __HIP_MEMORY_SCOPE_AGENT);
}
__device__ __forceinline__ void ast32i(int* p, int v) {
  __hip_atomic_store(p, v, __ATOMIC_RELAXED, __HIP_MEMORY_SCOPE_AGENT);
}
__device__ __forceinline__ void ast32f(float* p, float v) {
  __hip_atomic_store((unsigned*)p, __builtin_bit_cast(unsigned, v),
                     __ATOMIC_RELAXED, __HIP_MEMORY_SCOPE_AGENT);
}
__device__ __forceinline__ f16x8 ald_f16x8(const f16* p) {
  U128 u; u.lo = ald64(p); u.hi = ald64(p + 4);
  return __builtin_bit_cast(f16x8, u);
}
__device__ __forceinline__ f32x4 ald_f32x4(const float* p) {
  U128 u; u.lo = ald64(p); u.hi = ald64(p + 2);
  return __builtin_bit_cast(f32x4, u);
}
__device__ __forceinline__ void vm_drain() {          // operand-free, safe
  asm volatile("s_waitcnt vmcnt(0)" ::: "memory");
}

// ---------------------------------------------------------------------------
// Setup: pack weights (per-WG MFMA-fragment order), biases, zero flags.
// Fragment conventions (16x16x32):
//   A-frag: lane l holds A[m=l&15][k=(l>>4)*8+i]
//   B-frag: lane l holds B[k=(l>>4)*8+i][n=l&15]
//   D:      lane l, reg r -> D[m=(l>>4)*4+r][n=l&15]
// ---------------------------------------------------------------------------
__global__ void lstm_setup(
    const float* __restrict__ Wih0, const float* __restrict__ Whh0,
    const float* __restrict__ bih0, const float* __restrict__ bhh0,
    const float* __restrict__ Whr0,
    const float* __restrict__ Wih1, const float* __restrict__ Whh1,
    const float* __restrict__ bih1, const float* __restrict__ bhh1,
    const float* __restrict__ Whr1,
    f16* __restrict__ Bsw, f16* __restrict__ Whrsw, float* __restrict__ bias,
    int* __restrict__ flags)
{
  const int blk = blockIdx.x, tid = threadIdx.x;
  if (blk < 16) {
    // gate weights: WG rows 512 = [i|f|g|o] x 128 units (local).
    // Bsw[wg][ks8][ntG32][lane][i]: B[k = ks*32+(l>>4)*8+i][rl = ntG*16+(l&15)]
    // rl: gate = rl>>7, unit = rl&127; grow = gate*1024 + w*128 + unit
    const int lyr = blk >> 3, w = blk & 7;
    const float* Whh = lyr ? Whh1 : Whh0;
    const float* Wih = lyr ? Wih1 : Wih0;
    f16* dst = Bsw + (size_t)blk * 131072;
    for (int e = tid; e < 131072; e += 256) {
      int i = e & 7, l = (e >> 3) & 63, ntG = (e >> 9) & 31, ks = e >> 14;
      int k  = ks * 32 + (l >> 4) * 8 + i;
      int rl = ntG * 16 + (l & 15);
      int grow = (rl >> 7) * 1024 + w * 128 + (rl & 127);
      float v = (k < 128) ? Whh[grow * 128 + k] : Wih[grow * 128 + (k - 128)];
      dst[e] = (f16)v;
    }
  } else if (blk < 32) {
    // proj weights: Whrsw[wg][pnG8][ks4][lane][i]:
    //   B[kl = ks*32+(l>>4)*8+i][p = pnG*16+(l&15)] = Whr[p][w*128+kl]
    const int q = blk - 16, lyr = q >> 3, w = q & 7;
    const float* Whr = lyr ? Whr1 : Whr0;
    f16* dst = Whrsw + (size_t)q * 16384;
    for (int e = tid; e < 16384; e += 256) {
      int i = e & 7, l = (e >> 3) & 63, ks = (e >> 9) & 3, pnG = e >> 11;
      int p  = pnG * 16 + (l & 15);
      int kl = ks * 32 + (l >> 4) * 8 + i;
      dst[e] = (f16)Whr[p * 1024 + w * 128 + kl];
    }
  } else if (blk == 32) {
    // bias[lyr][w][rl]: rl = gate*128 + unit
    for (int e = tid; e < 8192; e += 256) {
      int lyr = e >> 12, w = (e >> 9) & 7, rl = e & 511;
      int grow = (rl >> 7) * 1024 + w * 128 + (rl & 127);
      bias[e] = lyr ? (bih1[grow] + bhh1[grow]) : (bih0[grow] + bhh0[grow]);
    }
  } else {
    if (tid < 24) ast32i(flags + tid, 0);
  }
}

// ---------------------------------------------------------------------------
// Main persistent kernel: 16 WGs x 512 thr (8 waves; wave wn owns gate
// N-tiles {wn+gate*8} = all 4 gates of units wn*16..+15, proj P-tile wn,
// all 4 M(batch)-tiles).
// ---------------------------------------------------------------------------
__global__ __launch_bounds__(512, 2) void lstm_main(
    const float* __restrict__ x, float* __restrict__ out,
    const f16* __restrict__ Bsw, const f16* __restrict__ Whrsw,
    const float* __restrict__ bias, float* __restrict__ slab,
    f16* __restrict__ ring, int* __restrict__ flags)
{
  const int tid = threadIdx.x;
  const int lane = tid & 63, wn = tid >> 6;
  const int l15 = lane & 15, lg = lane >> 4;
  const int w = blockIdx.x & 7, lyr = blockIdx.x >> 3;

  const u64 tstart = __builtin_amdgcn_s_memrealtime();
  bool tmo = false;

  __shared__ __align__(16) f16 h_lds[64][136];   // h_{t-1} (272B rows)
  __shared__ __align__(16) f16 s_lds[64][136];   // s values
  __shared__ int s_go;

  for (int e = tid; e < 64 * 136; e += 512) ((f16*)h_lds)[e] = (f16)0.f;
  if (tid == 0) s_go = 0;

  // ---- register-resident weights ----
  f16x8 bf[8][4];   // [ks][gate]; N-tile = gate*8 + wn
  {
    const f16* bsl = Bsw + (size_t)(lyr * NWG + w) * 131072;
#pragma unroll
    for (int ks = 0; ks < 8; ++ks)
#pragma unroll
      for (int g = 0; g < 4; ++g)
        bf[ks][g] = *(const f16x8*)(bsl + ((size_t)(ks * 32 + g * 8 + wn) * 64 + lane) * 8);
  }
  f16x8 wf[4];      // proj B-frags, P-tile wn
  {
    const f16* wsl = Whrsw + (size_t)(lyr * NWG + w) * 16384;
#pragma unroll
    for (int ks = 0; ks < 4; ++ks)
      wf[ks] = *(const f16x8*)(wsl + ((size_t)(wn * 4 + ks) * 64 + lane) * 8);
  }
  float bias_r[4];
#pragma unroll
  for (int g = 0; g < 4; ++g)
    bias_r[g] = bias[(lyr * 8 + w) * 512 + g * 128 + wn * 16 + l15];

  float c[4][4] = {{0,0,0,0},{0,0,0,0},{0,0,0,0},{0,0,0,0}};  // [mtl][r]

  int* f2 = flags + 16;
  float* slabL = slab + (size_t)lyr * 4 * 8 * 8192;
  __syncthreads();

  for (int t = 0; t <= TSTEPS; ++t) {
    const bool tail = (t == TSTEPS);

    // ================= poll (wave 0; others spin on LDS token) =============
    if (wn == 0) {
      for (;;) {
        bool ok = true;
        if (lyr == 0) {
          if (lane < 8)       ok = ald32i(flags + lane) >= t;        // own: slabs(t-1)
          else if (lane < 16) ok = ald32i(flags + lane) >= t - 4;    // l1 throttle (ring reuse)
        } else {
          if (lane < 8)       ok = tail ? true : (ald32i(f2 + lane) >= t + 1); // h1_t ready
          else if (lane < 16) ok = ald32i(flags + lane) >= t;        // own: slabs(t-1)
        }
        if ((__builtin_amdgcn_s_memrealtime() - tstart) > TIMEOUT_TICKS) { ok = true; tmo = true; }
        if (__all(ok)) break;
        __builtin_amdgcn_s_sleep(1);
      }
      __atomic_store_n(&s_go, t + 1, __ATOMIC_RELAXED);
    } else {
      while (__atomic_load_n(&s_go, __ATOMIC_RELAXED) < t + 1)
        __builtin_amdgcn_s_sleep(1);
    }
    asm volatile("" ::: "memory");

    // ================= sum phase: h_{t-1} = sum of own 8 slabs =============
    // thread owns f32 [q*2048 + tid*4 .. +3] for q=0..3  (b=q*16+(tid>>5),
    // p0=(tid*4)&127) -- fully coalesced 1KB/wave bursts.
    if (t > 0) {
      const float* sb = slabL + (size_t)((t - 1) & 3) * 8 * 8192;
      f32x4 hsum[4] = {{0,0,0,0},{0,0,0,0},{0,0,0,0},{0,0,0,0}};
#pragma unroll
      for (int s = 0; s < 8; ++s)
#pragma unroll
        for (int q = 0; q < 4; ++q)
          hsum[q] += ald_f32x4(sb + (size_t)s * 8192 + q * 2048 + tid * 4);

      const int p0 = (tid * 4) & 127;
#pragma unroll
      for (int q = 0; q < 4; ++q) {
        const int b = q * 16 + (tid >> 5);
        f16x4 hv;
#pragma unroll
        for (int e = 0; e < 4; ++e) hv[e] = (f16)hsum[q][e];
        *(f16x4*)(&h_lds[b][p0]) = hv;
        if (lyr == 1 && t - 1 >= TSTEPS - 64)
          *(f32x4*)(out + (size_t)b * 8192 + (t - 1 - (TSTEPS - 64)) * 128 + p0) = hsum[q];
      }
      // l0: post h1_{t-1} slice (p in [w*16,w*16+16)) to ring, A-frag layout
      if (lyr == 0 && ((tid >> 2) & 7) == w) {
        f16* rs = ring + (size_t)((t - 1) & 3) * 8192;
#pragma unroll
        for (int q = 0; q < 4; ++q) {
          const int b = q * 16 + (tid >> 5);
          f16x4 hv;
#pragma unroll
          for (int e = 0; e < 4; ++e) hv[e] = (f16)hsum[q][e];
          const int fl = (((p0 >> 5) * 4 + (b >> 4)) * 64 +
                          ((p0 & 31) >> 3) * 16 + (b & 15)) * 8 + (p0 & 7);
          ast64(rs + fl, __builtin_bit_cast(u64, hv));
        }
      }
    }
    vm_drain();        // ring stores (l0) / slab-sum loads at MALL
    __syncthreads();   // h_lds complete; all ring stores drained
    if (lyr == 0 && tid == 0 && t > 0) ast32i(f2 + w, t);  // h1_{t-1} posted
    if (tail) break;

    // ================= gates: [64,256]x[256,512], per M-tile ===============
    {
      const f16* rsrc = ring + (size_t)(t & 3) * 8192;
#pragma unroll
      for (int mtl = 0; mtl < 4; ++mtl) {
        f16x8 af[8];
#pragma unroll
        for (int ks = 0; ks < 4; ++ks)
          af[ks] = *(const f16x8*)(&h_lds[mtl * 16 + l15][ks * 32 + lg * 8]);
        if (lyr == 0) {
          const float* xp = x + ((size_t)(mtl * 16 + l15) * TSTEPS + t) * 128 + lg * 8;
#pragma unroll
          for (int ks2 = 0; ks2 < 4; ++ks2) {
            f32x4 v0 = *(const f32x4*)(xp + ks2 * 32);
            f32x4 v1 = *(const f32x4*)(xp + ks2 * 32 + 4);
            f16x8 hx;
            hx[0]=(f16)v0[0]; hx[1]=(f16)v0[1]; hx[2]=(f16)v0[2]; hx[3]=(f16)v0[3];
            hx[4]=(f16)v1[0]; hx[5]=(f16)v1[1]; hx[6]=(f16)v1[2]; hx[7]=(f16)v1[3];
            af[4 + ks2] = hx;
          }
        } else {
#pragma unroll
          for (int ks2 = 0; ks2 < 4; ++ks2)
            af[4 + ks2] = ald_f16x8(rsrc + ((size_t)(ks2 * 4 + mtl) * 64 + lane) * 8);
        }
        f32x4 acc[4];
#pragma unroll
        for (int g = 0; g < 4; ++g) {
          f32x4 b4 = {bias_r[g], bias_r[g], bias_r[g], bias_r[g]};
          acc[g] = b4;
        }
#pragma unroll
        for (int ks = 0; ks < 8; ++ks)
#pragma unroll
          for (int g = 0; g < 4; ++g)
            acc[g] = __builtin_amdgcn_mfma_f32_16x16x32_f16(af[ks], bf[ks][g], acc[g], 0, 0, 0);
        // elementwise: batch = mtl*16+lg*4+r, unit = wn*16+l15
#pragma unroll
        for (int r = 0; r < 4; ++r) {
          float gi = acc[0][r], gf = acc[1][r], gg = acc[2][r], go = acc[3][r];
          float cc = sigm(gf) * c[mtl][r] + sigm(gi) * tanh_(gg);
          c[mtl][r] = cc;
          float s = sigm(go) * tanh_(cc);
          s_lds[mtl * 16 + lg * 4 + r][wn * 16 + l15] = (f16)s;
        }
      }
    }
    __syncthreads();

    // ================= proj: [64,128]x[128,128], P-tile wn =================
    {
      float* sdst = slabL + (size_t)(t & 3) * 8 * 8192 + (size_t)w * 8192;
#pragma unroll
      for (int pml = 0; pml < 4; ++pml) {
        f32x4 pa = {0.f, 0.f, 0.f, 0.f};
#pragma unroll
        for (int ks = 0; ks < 4; ++ks) {
          f16x8 ap = *(const f16x8*)(&s_lds[pml * 16 + l15][ks * 32 + lg * 8]);
          pa = __builtin_amdgcn_mfma_f32_16x16x32_f16(ap, wf[ks], pa, 0, 0, 0);
        }
#pragma unroll
        for (int r = 0; r < 4; ++r)
          ast32f(sdst + (pml * 16 + lg * 4 + r) * 128 + wn * 16 + l15, pa[r]);
      }
    }
    vm_drain();
    __syncthreads();
    if (tid == 0) ast32i(flags + lyr * 8 + w, t + 1);
  }

  if (tmo && tid == 0) out[0] = 12345.0f;  // livelock canary
}

extern "C" void kernel_launch(void* const* d_in, const int* in_sizes, int n_in,
                              void* d_out, int out_size, void* d_ws, size_t ws_size,
                              hipStream_t stream)
{
  const float* x    = (const float*)d_in[0];
  const float* Wih0 = (const float*)d_in[1];
  const float* Whh0 = (const float*)d_in[2];
  const float* bih0 = (const float*)d_in[3];
  const float* bhh0 = (const float*)d_in[4];
  const float* Whr0 = (const float*)d_in[5];
  const float* Wih1 = (const float*)d_in[6];
  const float* Whh1 = (const float*)d_in[7];
  const float* bih1 = (const float*)d_in[8];
  const float* bhh1 = (const float*)d_in[9];
  const float* Whr1 = (const float*)d_in[10];

  if (ws_size < WS_NEED) return;

  char* ws = (char*)d_ws;
  f16*   Bsw   = (f16*)(ws + BSW_OFF);
  f16*   Whrsw = (f16*)(ws + WHR_OFF);
  float* bias  = (float*)(ws + BIAS_OFF);
  float* slab  = (float*)(ws + SLAB_OFF);
  f16*   ring  = (f16*)(ws + RING_OFF);
  int*   flags = (int*)(ws + FLAG_OFF);

  lstm_setup<<<34, 256, 0, stream>>>(Wih0, Whh0, bih0, bhh0, Whr0,
                                     Wih1, Whh1, bih1, bhh1, Whr1,
                                     Bsw, Whrsw, bias, flags);
  lstm_main<<<16, 512, 0, stream>>>(x, (float*)d_out, Bsw, Whrsw, bias,
                                    slab, ring, flags);
}

// Round 7
// 17881.683 us; speedup vs baseline: 2.4004x; 2.4004x over previous
//
#include <hip/hip_runtime.h>
#include <hip/hip_fp16.h>

// ============================================================================
// 2-layer LSTM with projection (proj_size=128, H=1024, B=64, T=2048)
//
// Round 7: one cross-WG hop via MALL f32 atomic-add accumulation.
//  - Geometry = round 5 (proven, VGPR 168, no spills): 32 WGs/layer x 256 thr,
//    gate weights register-resident (bf[8][4] = 128 VGPR), fp32 c-state.
//    Round 6's regression was __launch_bounds__(512,2) capping VGPRs at 128
//    -> weights reloaded every step; reverted.
//  - Per step per WG: poll 2 counter dwords -> read h_{t-1} f32 (32KB, sc1)
//    [-> l1 also reads h1_t from l0's accumulator] -> f16 to LDS -> gate MFMA
//    [64,256]x[256,128] -> elementwise -> proj MFMA [64,32]x[32,128] ->
//    8192x global_atomic_add_f32 into h-accumulator slot -> drain -> one
//    cumulative counter inc. No slabs, no reduce phase, no f16 ring.
//  - Slot ring depth 8; WG zeroes its p-slice of slot (t+4) during step t.
//    Lockstep counters order zero -> add -> read -> re-zero provably.
//  - Throttles: l0 step t waits counter1 >= 32(t-3) (l1 read h1[t-4] done);
//    l1 step t waits counter0 >= 32(t+1) (h1_t complete) + own >= 32t.
//  - All cross-WG data via round-5-proven relaxed AGENT atomics (sc1, MALL-
//    coherent, zero cache-maintenance). Timeout + canary kept.
// ============================================================================

typedef _Float16 f16;
typedef _Float16 f16x4 __attribute__((ext_vector_type(4)));
typedef _Float16 f16x8 __attribute__((ext_vector_type(8)));
typedef float f32x4 __attribute__((ext_vector_type(4)));
typedef unsigned long long u64;
struct U128 { u64 lo, hi; };

#define TSTEPS 2048
#define NW 32
#define TIMEOUT_TICKS 200000000ull   // ~2 s at 100 MHz s_memrealtime

// ---- workspace layout (bytes) ----
#define BSW_OFF  0ull
#define BSW_SZ   (64ull*32768ull*2ull)        // gate weights, 4 MiB
#define WHR_OFF  (BSW_OFF + BSW_SZ)
#define WHR_SZ   (64ull*4096ull*2ull)         // proj weights, 512 KiB
#define BIAS_OFF (WHR_OFF + WHR_SZ)
#define BIAS_SZ  (8192ull*4ull)
#define HACC_OFF (BIAS_OFF + BIAS_SZ)
#define HACC_SZ  (2ull*8ull*8192ull*4ull)     // [lyr][slot8][64b x 128p] f32
#define CNT_OFF  (HACC_OFF + HACC_SZ)
#define CNT_SZ   (256ull)
#define WS_NEED  (CNT_OFF + CNT_SZ)

__device__ __forceinline__ float sigm(float v) {
  float e = __builtin_amdgcn_exp2f(-1.4426950408889634f * v);
  return __builtin_amdgcn_rcpf(1.0f + e);
}
__device__ __forceinline__ float tanh_(float v) {
  float a = fabsf(v);
  float e = __builtin_amdgcn_exp2f(-2.8853900817779268f * a);
  float r = (1.0f - e) * __builtin_amdgcn_rcpf(1.0f + e);
  return copysignf(r, v);
}

// ---- relaxed agent-scope atomic helpers (compile to global_* sc1) --------
__device__ __forceinline__ u64 ald64(const void* p) {
  return __hip_atomic_load((const u64*)p, __ATOMIC_RELAXED, __HIP_MEMORY_SCOPE_AGENT);
}
__device__ __forceinline__ unsigned ald32u(const unsigned* p) {
  return __hip_atomic_load(p, __ATOMIC_RELAXED, __HIP_MEMORY_SCOPE_AGENT);
}
__device__ __forceinline__ void ast32f(float* p, float v) {
  __hip_atomic_store((unsigned*)p, __builtin_bit_cast(unsigned, v),
                     __ATOMIC_RELAXED, __HIP_MEMORY_SCOPE_AGENT);
}
__device__ __forceinline__ void ast32u(unsigned* p, unsigned v) {
  __hip_atomic_store(p, v, __ATOMIC_RELAXED, __HIP_MEMORY_SCOPE_AGENT);
}
__device__ __forceinline__ f32x4 ald_f32x4(const float* p) {
  U128 u; u.lo = ald64(p); u.hi = ald64(p + 2);
  return __builtin_bit_cast(f32x4, u);
}
__device__ __forceinline__ void aadd_f32(float* p, float v) {
  (void)__hip_atomic_fetch_add(p, v, __ATOMIC_RELAXED, __HIP_MEMORY_SCOPE_AGENT);
}
__device__ __forceinline__ void vm_drain() {
  asm volatile("s_waitcnt vmcnt(0)" ::: "memory");
}

// ---------------------------------------------------------------------------
// Setup (round-5-proven weight packing). Fragment conventions (16x16x32):
//   A-frag: lane l holds A[m=l&15][k=(l>>4)*8+i]
//   B-frag: lane l holds B[k=(l>>4)*8+i][n=l&15]
//   D:      lane l, reg r -> D[m=(l>>4)*4+r][n=l&15]
// ---------------------------------------------------------------------------
__global__ void lstm_setup(
    const float* __restrict__ Wih0, const float* __restrict__ Whh0,
    const float* __restrict__ bih0, const float* __restrict__ bhh0,
    const float* __restrict__ Whr0,
    const float* __restrict__ Wih1, const float* __restrict__ Whh1,
    const float* __restrict__ bih1, const float* __restrict__ bhh1,
    const float* __restrict__ Whr1,
    f16* __restrict__ Bsw, f16* __restrict__ Whrsw, float* __restrict__ bias,
    float* __restrict__ hacc, unsigned* __restrict__ cnt)
{
  const int blk = blockIdx.x, tid = threadIdx.x;
  if (blk < 64) {
    const int lyr = blk >> 5, w = blk & 31;
    const float* Whh = lyr ? Whh1 : Whh0;
    const float* Wih = lyr ? Wih1 : Wih0;
    f16* dst = Bsw + (size_t)blk * 32768;
    for (int e = tid; e < 32768; e += 256) {
      int i = e & 7, l = (e >> 3) & 63, ntG = (e >> 9) & 7, ks = e >> 12;
      int k  = ks * 32 + (l >> 4) * 8 + i;
      int rl = ntG * 16 + (l & 15);
      int grow = (rl >> 5) * 1024 + w * 32 + (rl & 31);
      float v = (k < 128) ? Whh[grow * 128 + k] : Wih[grow * 128 + (k - 128)];
      dst[e] = (f16)v;
    }
  } else if (blk < 128) {
    const int q = blk - 64, lyr = q >> 5, w = q & 31;
    const float* Whr = lyr ? Whr1 : Whr0;
    f16* dst = Whrsw + (size_t)q * 4096;
    for (int e = tid; e < 4096; e += 256) {
      int i = e & 7, l = (e >> 3) & 63, pnG = e >> 9;
      int p = pnG * 16 + (l & 15);
      int hg = w * 32 + (l >> 4) * 8 + i;
      dst[e] = (f16)Whr[p * 1024 + hg];
    }
  } else if (blk == 128) {
    for (int e = tid; e < 8192; e += 256) {
      int lyr = e >> 12, j = e & 4095;
      bias[e] = lyr ? (bih1[j] + bhh1[j]) : (bih0[j] + bhh0[j]);
    }
  } else {
    // zero both h-accumulator rings (agent stores) + counters
    for (int e = tid; e < 2 * 8 * 8192; e += 256) ast32f(hacc + e, 0.f);
    if (tid < 64) ast32u(cnt + tid, 0u);
  }
}

// ---------------------------------------------------------------------------
// Main persistent kernel: 64 WGs x 256 thr (4 waves, (wy,wx) 2x2; round-5
// wave mapping: gate M-tiles {wy*2,wy*2+1}, gate N-tiles {ntl*2+wx} with
// ntl = gate type; proj P-tiles {pnl*2+wx}).
// ---------------------------------------------------------------------------
__global__ __launch_bounds__(256, 1) void lstm_main(
    const float* __restrict__ x, float* __restrict__ out,
    const f16* __restrict__ Bsw, const f16* __restrict__ Whrsw,
    const float* __restrict__ bias, float* __restrict__ hacc,
    unsigned* __restrict__ cnt)
{
  const int tid = threadIdx.x;
  const int lane = tid & 63, wv = tid >> 6;
  const int wy = wv >> 1, wx = wv & 1;
  const int l15 = lane & 15, lg = lane >> 4;
  const int w = blockIdx.x & 31, lyr = blockIdx.x >> 5;

  const u64 tstart = __builtin_amdgcn_s_memrealtime();
  bool tmo = false;

  __shared__ __align__(16) f16 h_lds[64][136];   // h_{t-1}, row=batch, col=p
  __shared__ __align__(16) f16 x1_lds[64][136];  // l1: h1_t
  __shared__ __align__(16) f16 s_lds[64][40];    // s, row=batch, 32 cols used
  __shared__ int s_go;
  if (tid == 0) s_go = 0;

  // ---- register-resident weights (round-5 packing) ----
  f16x8 bf[8][4];
  {
    const f16* bsl = Bsw + (size_t)(lyr * NW + w) * 32768;
#pragma unroll
    for (int ks = 0; ks < 8; ++ks)
#pragma unroll
      for (int ntl = 0; ntl < 4; ++ntl)
        bf[ks][ntl] = *(const f16x8*)(bsl + (((ks * 8 + (ntl * 2 + wx)) * 64 + lane) * 8));
  }
  f16x8 wf[4];
  {
    const f16* wsl = Whrsw + (size_t)(lyr * NW + w) * 4096;
#pragma unroll
    for (int pnl = 0; pnl < 4; ++pnl)
      wf[pnl] = *(const f16x8*)(wsl + (((pnl * 2 + wx) * 64 + lane) * 8));
  }
  float bias_r[4];
#pragma unroll
  for (int ntl = 0; ntl < 4; ++ntl)
    bias_r[ntl] = bias[lyr * 4096 + ntl * 1024 + w * 32 + wx * 16 + l15];

  float c[2][4] = {{0.f,0.f,0.f,0.f},{0.f,0.f,0.f,0.f}};

  float* myacc = hacc + (size_t)lyr * 8 * 8192;   // own layer's accumulator ring
  float* h1a   = hacc;                            // layer-0 accumulator ring
  unsigned* c0 = cnt;
  unsigned* c1 = cnt + 1;
  __syncthreads();

  for (int t = 0; t <= TSTEPS; ++t) {
    if (lyr == 0 && t == TSTEPS) break;          // l0 has no tail work
    const bool tail = (t == TSTEPS);             // only reachable for l1

    // ---- prefetch x_t (l0; plain cached loads of read-only input) ----
    f16x8 xr[2][4];
    if (lyr == 0) {
#pragma unroll
      for (int mtl = 0; mtl < 2; ++mtl) {
        const int bbx = (wy * 2 + mtl) * 16 + l15;
        const float* xp = x + ((size_t)bbx * TSTEPS + t) * 128 + lg * 8;
#pragma unroll
        for (int ks2 = 0; ks2 < 4; ++ks2) {
          f32x4 v0 = *(const f32x4*)(xp + ks2 * 32);
          f32x4 v1 = *(const f32x4*)(xp + ks2 * 32 + 4);
          f16x8 hx;
          hx[0]=(f16)v0[0]; hx[1]=(f16)v0[1]; hx[2]=(f16)v0[2]; hx[3]=(f16)v0[3];
          hx[4]=(f16)v1[0]; hx[5]=(f16)v1[1]; hx[6]=(f16)v1[2]; hx[7]=(f16)v1[3];
          xr[mtl][ks2] = hx;
        }
      }
    }

    // ================= poll: 2 counter dwords (wave 0; LDS token) ==========
    if (wv == 0) {
      for (;;) {
        bool ok = true;
        if (lane == 0) {            // own-layer recurrence: h_{t-1} complete
          ok = ald32u(lyr ? c1 : c0) >= (unsigned)(32 * t);
        } else if (lane == 1) {     // other-layer condition
          if (lyr == 0) ok = (t < 4) || (ald32u(c1) >= (unsigned)(32 * (t - 3)));
          else          ok = tail || (ald32u(c0) >= (unsigned)(32 * (t + 1)));
        }
        if ((__builtin_amdgcn_s_memrealtime() - tstart) > TIMEOUT_TICKS) { ok = true; tmo = true; }
        if (__all(ok)) break;
        __builtin_amdgcn_s_sleep(1);
      }
      __atomic_store_n(&s_go, t + 1, __ATOMIC_RELAXED);
    } else {
      while (__atomic_load_n(&s_go, __ATOMIC_RELAXED) < t + 1)
        __builtin_amdgcn_s_sleep(1);
    }
    asm volatile("" ::: "memory");

    // ================= read phase: h_{t-1} (+ h1_t for l1) -> LDS ==========
    {
      const int b = tid >> 2, pb = (tid & 3) * 32;       // 32 f32 per thread
      const float* hp = myacc + (size_t)((t + 7) & 7) * 8192 + b * 128 + pb;
      f32x4 hv4[8];
#pragma unroll
      for (int k = 0; k < 8; ++k) hv4[k] = ald_f32x4(hp + k * 4);
      // out rows come from h2_{t-1} (l1), slice owned by this WG
      if (lyr == 1 && t >= TSTEPS - 63 && (tid & 3) == (w >> 3))
        *(f32x4*)(out + (size_t)b * 8192 + (t - 1 - (TSTEPS - 64)) * 128 + w * 4) = hv4[w & 7];
#pragma unroll
      for (int k = 0; k < 8; ++k) {
        f16x4 h16;
#pragma unroll
        for (int e = 0; e < 4; ++e) h16[e] = (f16)hv4[k][e];
        *(f16x4*)(&h_lds[b][pb + k * 4]) = h16;
      }
      if (lyr == 1 && !tail) {
        const float* xp1 = h1a + (size_t)(t & 7) * 8192 + b * 128 + pb;
#pragma unroll
        for (int k = 0; k < 8; ++k) {
          f32x4 v = ald_f32x4(xp1 + k * 4);
          f16x4 h16;
#pragma unroll
          for (int e = 0; e < 4; ++e) h16[e] = (f16)v[e];
          *(f16x4*)(&x1_lds[b][pb + k * 4]) = h16;
        }
      }
      // zero our p-slice of slot t+4 (holds h[t-4]; all reads of it are done
      // by counter-lockstep; visible to t+4 adders via our counter inc)
      if (!tail)
        ast32f(myacc + (size_t)((t + 4) & 7) * 8192 + b * 128 + w * 4 + (tid & 3), 0.f);
    }
    if (tail) break;   // uniform for all l1 threads
    __syncthreads();

    // ================= gates: [64,256]x[256,128] per M-tile ================
#pragma unroll
    for (int mtl = 0; mtl < 2; ++mtl) {
      f16x8 af[8];
#pragma unroll
      for (int ks = 0; ks < 4; ++ks)
        af[ks] = *(const f16x8*)(&h_lds[(wy * 2 + mtl) * 16 + l15][ks * 32 + lg * 8]);
      if (lyr == 0) {
        af[4] = xr[mtl][0]; af[5] = xr[mtl][1];
        af[6] = xr[mtl][2]; af[7] = xr[mtl][3];
      } else {
#pragma unroll
        for (int ks2 = 0; ks2 < 4; ++ks2)
          af[4 + ks2] = *(const f16x8*)(&x1_lds[(wy * 2 + mtl) * 16 + l15][ks2 * 32 + lg * 8]);
      }
      f32x4 acc[4];
#pragma unroll
      for (int ntl = 0; ntl < 4; ++ntl) {
        f32x4 b4 = {bias_r[ntl], bias_r[ntl], bias_r[ntl], bias_r[ntl]};
        acc[ntl] = b4;
      }
#pragma unroll
      for (int ks = 0; ks < 8; ++ks)
#pragma unroll
        for (int ntl = 0; ntl < 4; ++ntl)
          acc[ntl] = __builtin_amdgcn_mfma_f32_16x16x32_f16(af[ks], bf[ks][ntl], acc[ntl], 0, 0, 0);
      // elementwise: ntl = gate type (i,f,g,o) for unit wx*16+l15
#pragma unroll
      for (int r = 0; r < 4; ++r) {
        float gi = acc[0][r], gf = acc[1][r], gg = acc[2][r], go = acc[3][r];
        float cc = sigm(gf) * c[mtl][r] + sigm(gi) * tanh_(gg);
        c[mtl][r] = cc;
        float s = sigm(go) * tanh_(cc);
        s_lds[(wy * 2 + mtl) * 16 + lg * 4 + r][wx * 16 + l15] = (f16)s;
      }
    }
    __syncthreads();

    // ================= proj [64,32]x[32,128] + atomic-add accumulate =======
    {
      float* dst = myacc + (size_t)(t & 7) * 8192;
#pragma unroll
      for (int pml = 0; pml < 2; ++pml) {
        f16x8 ap = *(const f16x8*)(&s_lds[(wy * 2 + pml) * 16 + l15][lg * 8]);
#pragma unroll
        for (int pnl = 0; pnl < 4; ++pnl) {
          f32x4 z = {0.f, 0.f, 0.f, 0.f};
          f32x4 pa = __builtin_amdgcn_mfma_f32_16x16x32_f16(ap, wf[pnl], z, 0, 0, 0);
          const int p = (pnl * 2 + wx) * 16 + l15;
#pragma unroll
          for (int r = 0; r < 4; ++r) {
            const int b = (wy * 2 + pml) * 16 + lg * 4 + r;
            aadd_f32(dst + b * 128 + p, pa[r]);
          }
        }
      }
    }
    vm_drain();        // adds + zero stores acked at MALL
    __syncthreads();   // all waves drained
    if (tid == 0)
      (void)__hip_atomic_fetch_add(lyr ? c1 : c0, 1u, __ATOMIC_RELAXED, __HIP_MEMORY_SCOPE_AGENT);
  }

  if (tmo && tid == 0) out[0] = 12345.0f;  // livelock canary
}

extern "C" void kernel_launch(void* const* d_in, const int* in_sizes, int n_in,
                              void* d_out, int out_size, void* d_ws, size_t ws_size,
                              hipStream_t stream)
{
  const float* x    = (const float*)d_in[0];
  const float* Wih0 = (const float*)d_in[1];
  const float* Whh0 = (const float*)d_in[2];
  const float* bih0 = (const float*)d_in[3];
  const float* bhh0 = (const float*)d_in[4];
  const float* Whr0 = (const float*)d_in[5];
  const float* Wih1 = (const float*)d_in[6];
  const float* Whh1 = (const float*)d_in[7];
  const float* bih1 = (const float*)d_in[8];
  const float* bhh1 = (const float*)d_in[9];
  const float* Whr1 = (const float*)d_in[10];

  if (ws_size < WS_NEED) return;

  char* ws = (char*)d_ws;
  f16*      Bsw   = (f16*)(ws + BSW_OFF);
  f16*      Whrsw = (f16*)(ws + WHR_OFF);
  float*    bias  = (float*)(ws + BIAS_OFF);
  float*    hacc  = (float*)(ws + HACC_OFF);
  unsigned* cnt   = (unsigned*)(ws + CNT_OFF);

  lstm_setup<<<130, 256, 0, stream>>>(Wih0, Whh0, bih0, bhh0, Whr0,
                                      Wih1, Whh1, bih1, bhh1, Whr1,
                                      Bsw, Whrsw, bias, hacc, cnt);
  lstm_main<<<64, 256, 0, stream>>>(x, (float*)d_out, Bsw, Whrsw, bias,
                                    hacc, cnt);
}